// Round 6
// baseline (334.200 us; speedup 1.0000x reference)
//
#include <hip/hip_runtime.h>

// Problem constants
#define E_DIM 1024
#define H_NUM 16
#define D_HEAD 64
#define SEQ 2048
#define BATCH 2
#define NTOK 4096      // BATCH*SEQ
#define R_LORA 128
#define Q3 3072        // 3*E_DIM
#define K_PRESCALE 0.125f  // 1/sqrt(64), exact in bf16

typedef float floatx4 __attribute__((ext_vector_type(4)));
typedef __bf16 bf16x8 __attribute__((ext_vector_type(8)));
typedef __bf16 bf16x4 __attribute__((ext_vector_type(4)));
typedef bf16x8 bf16x8_al __attribute__((may_alias));
typedef bf16x4 bf16x4_al __attribute__((may_alias));

// async global->LDS, 16B per lane; lds dst must be wave-uniform (HW adds lane*16)
__device__ __forceinline__ void async_cp16(const void* g, void* l) {
  __builtin_amdgcn_global_load_lds(
      (__attribute__((address_space(1))) unsigned int*)(size_t)g,
      (__attribute__((address_space(3))) unsigned int*)l, 16, 0, 0);
}

// ---------------- fused prep kernel (one launch) ----------------
// [0,4096) x->xb | [4096,7168) weff rows (into wtot) | [7168,7552) binb
// [7552,7584) aeffT (fold+transpose) | [7584,8608) wo
__global__ __launch_bounds__(256) void prep_all(const float* __restrict__ x,
                                                const float* __restrict__ Wi,
                                                const float* __restrict__ Bl,
                                                const float* __restrict__ Ai,
                                                const float* __restrict__ Wo,
                                                __bf16* __restrict__ xb,
                                                __bf16* __restrict__ wtot,
                                                __bf16* __restrict__ binb,
                                                __bf16* __restrict__ aeffT,
                                                __bf16* __restrict__ wob) {
  __shared__ __bf16 tile[64][65];
  const int blk = blockIdx.x, t = threadIdx.x;
  if (blk < 4096) {                       // x (4096x1024 fp32) -> xb bf16 (contig)
    int idx = (blk * 256 + t) * 4;
    float4 v = *(const float4*)(x + idx);
    bf16x4 o = {(__bf16)v.x, (__bf16)v.y, (__bf16)v.z, (__bf16)v.w};
    *(bf16x4_al*)(xb + idx) = o;
  } else if (blk < 7168) {                // weff row j: fold 3 E-blocks of W_in -> wtot
    int j = blk - 4096, e = t * 4;
    const float* r = Wi + (size_t)j * Q3;
    float4 a = *(const float4*)(r + e);
    float4 b = *(const float4*)(r + e + 1024);
    float4 c = *(const float4*)(r + e + 2048);
    bf16x4 o = {(__bf16)(a.x + b.x + c.x), (__bf16)(a.y + b.y + c.y),
                (__bf16)(a.z + b.z + c.z), (__bf16)(a.w + b.w + c.w)};
    *(bf16x4_al*)(wtot + (size_t)j * E_DIM + e) = o;
  } else if (blk < 7552) {                // binb: B_in cast, dense [3072][128]
    int idx = (blk - 7168) * 256 + t;     // quad id over 3072x32
    int j = idx >> 5, cq = (idx & 31) * 4;
    float4 v = *(const float4*)(Bl + (size_t)j * R_LORA + cq);
    bf16x4 o = {(__bf16)v.x, (__bf16)v.y, (__bf16)v.z, (__bf16)v.w};
    *(bf16x4_al*)(binb + (size_t)j * R_LORA + cq) = o;
  } else if (blk < 7584) {                // aeffT[e][r] = fold of A_in, via LDS transpose
    int b2 = blk - 7552;
    int r0 = (b2 & 1) * 64, e0 = (b2 >> 1) * 64;
    int c = t & 63, r4 = t >> 6;
#pragma unroll
    for (int i = 0; i < 16; i++) {
      int row = r4 + i * 4;  // local r
      const float* rp = Ai + (size_t)(r0 + row) * Q3 + e0 + c;
      tile[row][c] = (__bf16)(rp[0] + rp[1024] + rp[2048]);
    }
    __syncthreads();
#pragma unroll
    for (int i = 0; i < 16; i++) {
      int er = r4 + i * 4;  // local e
      aeffT[(size_t)(e0 + er) * R_LORA + r0 + c] = tile[c][er];
    }
  } else {                                // wo cast
    int idx = ((blk - 7584) * 256 + t) * 4;
    float4 v = *(const float4*)(Wo + idx);
    bf16x4 o = {(__bf16)v.x, (__bf16)v.y, (__bf16)v.z, (__bf16)v.w};
    *(bf16x4_al*)(wob + idx) = o;
  }
}

// ---------------- TMx128 MFMA GEMM: D[m][n] = sum_k A[m][k]*B[n][k] ----------------
// TM=128: 4 waves in 2x2, acc[4][4]. TM=64: waves 1x4 (all share rows), acc[4][2].
// EPI 0: fp32 store, ldc=1024 (out-proj)
// EPI 1: qkv scatter; Q,K -> [bh][s][d] (K pre-scaled by 0.125); V -> V^T [bh][d][s] b64
// EPI 3: wtot in-place: o0[row*1024+col] += acc*(1/128) (LoRA weight fold)
template <int TM, int KTOT, int LDA, int LDB, int EPI>
__global__ __launch_bounds__(256) void gemm_mfma(const __bf16* A, const __bf16* Bm,
                                                 float* fOut, __bf16* o0, __bf16* o1,
                                                 __bf16* o2) {
  constexpr int NSEG_A = TM / 16;       // 8 or 4
  constexpr int NSEG = NSEG_A + 8;      // 16 or 12
  constexpr int SPW = NSEG / 4;         // 4 or 3
  constexpr int NJ = (TM == 128) ? 4 : 2;
  __shared__ __bf16 lds[NSEG * 512];
  const int t = threadIdx.x;
  const int wave = t >> 6, lane = t & 63;
  const int lr = lane & 15, lq = lane >> 4;
  const int m0 = blockIdx.x * TM, n0 = blockIdx.y * 128;
  const int aw = (TM == 128) ? (wave & 1) * 4 : 0;        // A frag base seg
  const int bw = (TM == 128) ? (wave >> 1) * 4 : wave * 2;  // B frag base seg

  floatx4 acc[4][NJ] = {};

  for (int kk = 0; kk < KTOT; kk += 32) {
    __syncthreads();  // prior frag reads done before overwrite
#pragma unroll
    for (int ii = 0; ii < SPW; ii++) {
      int s = wave * SPW + ii;
      const __bf16* src =
          (s < NSEG_A)
              ? A + (size_t)(m0 + s * 16 + lr) * LDA + kk + lq * 8
              : Bm + (size_t)(n0 + (s - NSEG_A) * 16 + lr) * LDB + kk + lq * 8;
      async_cp16(src, lds + s * 512);
    }
    __syncthreads();  // drains vmcnt -> staging visible
    bf16x8 af[4], bfr[NJ];
#pragma unroll
    for (int i = 0; i < 4; i++)
      af[i] = *(const bf16x8_al*)(lds + (aw + i) * 512 + lane * 8);
#pragma unroll
    for (int j = 0; j < NJ; j++)
      bfr[j] = *(const bf16x8_al*)(lds + (NSEG_A + bw + j) * 512 + lane * 8);
#pragma unroll
    for (int i = 0; i < 4; i++)
#pragma unroll
      for (int j = 0; j < NJ; j++)
        acc[i][j] = __builtin_amdgcn_mfma_f32_16x16x32_bf16(af[i], bfr[j], acc[i][j], 0, 0, 0);
  }

#pragma unroll
  for (int i = 0; i < 4; i++)
#pragma unroll
    for (int j = 0; j < NJ; j++) {
      const int row0 = m0 + ((TM == 128) ? (wave & 1) * 64 : 0) + i * 16 + lq * 4;
      const int col = n0 + ((TM == 128) ? (wave >> 1) * 64 : wave * 32) + j * 16 + lr;
      if (EPI == 0) {
#pragma unroll
        for (int r = 0; r < 4; r++)
          fOut[(size_t)(row0 + r) * 1024 + col] = acc[i][j][r];
      } else if (EPI == 3) {
#pragma unroll
        for (int r = 0; r < 4; r++) {
          size_t off = (size_t)(row0 + r) * 1024 + col;
          o0[off] = (__bf16)((float)o0[off] + acc[i][j][r] * (1.0f / 128.0f));
        }
      } else {
        int part = col >> 10, e = col & 1023, h = e >> 6, d = e & 63;
        int b = row0 >> 11, s = row0 & 2047;
        if (part == 2) {
          // V^T [bh][d][s]: 4 consecutive s in one lane -> packed b64 store
          bf16x4 pv;
#pragma unroll
          for (int r = 0; r < 4; r++) pv[r] = (__bf16)acc[i][j][r];
          *(bf16x4_al*)(o2 + ((size_t)(b * H_NUM + h) * D_HEAD + d) * SEQ + s) = pv;
        } else {
#pragma unroll
          for (int r = 0; r < 4; r++) {
            float v = acc[i][j][r];
            if (part == 1) v *= K_PRESCALE;  // fold softmax 1/sqrt(D) into K
            size_t off = ((size_t)(b * H_NUM + h) * SEQ + (s + r)) * D_HEAD + d;
            (part == 0 ? o0 : o1)[off] = (__bf16)v;
          }
        }
      }
    }
}

// ---------------- flash attention v6: v3 body, 2-wave blocks for occupancy ----------------
// 32 q-rows/block (16/wave), 64-key tiles, single-buffer LDS, proven two-barrier
// staging. 20 KB LDS -> 8 blocks/CU = 16 waves/CU. S^T = K x Q; P^T b64 pack via
// XOR-swizzled wave-private LDS; max-free softmax (K pre-scaled 1/8).
__global__ __launch_bounds__(128, 4) void attn_kernel(const __bf16* __restrict__ Q,
                                                      const __bf16* __restrict__ K,
                                                      const __bf16* __restrict__ Vt,
                                                      __bf16* __restrict__ O) {
  __shared__ __bf16 smem[4096 + 4096 + 2048];  // kls[8][512] | vls[8][512] | pls[2][1024]
  __bf16* kls = smem;
  __bf16* vls = smem + 4096;
  const int t = threadIdx.x, wave = t >> 6, lane = t & 63;
  const int lr = lane & 15, lq = lane >> 4;
  __bf16* plsw = smem + 8192 + wave * 1024;  // per-wave P: [q=16][key=64], swizzled chunks
  const int bh = blockIdx.y, q0 = blockIdx.x * 32;
  const size_t hbase = (size_t)bh * SEQ * D_HEAD;
  const __bf16* Kp = K + hbase;
  const __bf16* vtb = Vt + (size_t)bh * D_HEAD * SEQ;
  const int row7 = lr & 7;

  // Q frags (B-operand: rows q = q0+wave*16+lr)
  bf16x8 qf0, qf1;
  {
    const __bf16* qp = Q + hbase + (size_t)(q0 + wave * 16 + lr) * D_HEAD + lq * 8;
    qf0 = *(const bf16x8_al*)qp;
    qf1 = *(const bf16x8_al*)(qp + 32);
  }

  floatx4 oacc[4] = {};
  float lsum = 0.0f;

  for (int kt = 0; kt < SEQ; kt += 64) {
    __syncthreads();  // prior tile's LDS reads complete before overwrite
    // stage 16 blocks (8 per wave): 0..7 = K (kb=s>>1, c=s&1), 8..15 = V (dg, kc)
#pragma unroll
    for (int ii = 0; ii < 8; ii++) {
      int s = wave * 8 + ii;
      const __bf16* src;
      if (s < 8) {
        src = Kp + (size_t)(kt + (s >> 1) * 16 + lr) * D_HEAD + (s & 1) * 32 + lq * 8;
      } else {
        int v = s - 8;
        src = vtb + (size_t)((v >> 1) * 16 + lr) * SEQ + kt + (v & 1) * 32 + lq * 8;
      }
      async_cp16(src, smem + s * 512);
    }
    __syncthreads();  // drains vmcnt -> staging visible

    // S^T (keys x q) + softmax + P^T pack
#pragma unroll
    for (int kb = 0; kb < 4; kb++) {
      bf16x8 kf0 = *(const bf16x8_al*)(kls + (kb * 2) * 512 + lane * 8);
      bf16x8 kf1 = *(const bf16x8_al*)(kls + (kb * 2 + 1) * 512 + lane * 8);
      floatx4 s = {};
      s = __builtin_amdgcn_mfma_f32_16x16x32_bf16(kf0, qf0, s, 0, 0, 0);
      s = __builtin_amdgcn_mfma_f32_16x16x32_bf16(kf1, qf1, s, 0, 0, 0);
      bf16x4 pv;
#pragma unroll
      for (int r = 0; r < 4; r++) {
        float p = __expf(s[r]);  // 1/sqrt(D) already folded into K
        lsum += p;
        pv[r] = (__bf16)p;
      }
      // lane holds keys kb*16+lq*4+{0..3} for q=lr -> one b64 store
      int chunk = (kb * 2 + (lq >> 1)) ^ row7;
      *(bf16x4_al*)(plsw + lr * 64 + chunk * 8 + (lq & 1) * 4) = pv;
    }

    // O += P @ V : A-frag P[q=lr][key=kc*32+lq*8+j], B-frag Vt[d][key]
#pragma unroll
    for (int kc = 0; kc < 2; kc++) {
      int chunk = (kc * 4 + lq) ^ row7;
      bf16x8 pf = *(const bf16x8_al*)(plsw + lr * 64 + chunk * 8);
#pragma unroll
      for (int jd = 0; jd < 4; jd++) {
        bf16x8 vf = *(const bf16x8_al*)(vls + (jd * 2 + kc) * 512 + lane * 8);
        oacc[jd] = __builtin_amdgcn_mfma_f32_16x16x32_bf16(pf, vf, oacc[jd], 0, 0, 0);
      }
    }
  }

  // reduce l across the 4 lanes sharing q=lr (lq groups)
  lsum += __shfl_xor(lsum, 16);
  lsum += __shfl_xor(lsum, 32);

  const int b = bh >> 4, h = bh & 15;
#pragma unroll
  for (int r = 0; r < 4; r++) {
    float linv = 1.0f / __shfl(lsum, lq * 4 + r);  // lane q_local holds l(q_local)
    int s = q0 + wave * 16 + lq * 4 + r;
#pragma unroll
    for (int jd = 0; jd < 4; jd++) {
      int d = jd * 16 + lr;
      O[((size_t)b * SEQ + s) * E_DIM + h * D_HEAD + d] = (__bf16)(oacc[jd][r] * linv);
    }
  }
}

// ---------------- launch ----------------
extern "C" void kernel_launch(void* const* d_in, const int* in_sizes, int n_in,
                              void* d_out, int out_size, void* d_ws, size_t ws_size,
                              hipStream_t stream) {
  const float* x  = (const float*)d_in[0];
  const float* Wi = (const float*)d_in[1];
  const float* Ai = (const float*)d_in[2];
  const float* Bi = (const float*)d_in[3];
  const float* Wo = (const float*)d_in[4];
  float* out = (float*)d_out;
  char* ws = (char*)d_ws;

  // workspace layout (bytes), ~49 MB
  __bf16* xb    = (__bf16*)(ws);                  // 4096x1024 bf16   8,388,608
  __bf16* wtot  = (__bf16*)(ws + 8388608);        // 3072x1024 bf16   6,291,456
  __bf16* binb  = (__bf16*)(ws + 14680064);       // 3072x128 bf16      786,432
  __bf16* aeffT = (__bf16*)(ws + 15466496);       // 1024x128 bf16      262,144
  __bf16* wob   = (__bf16*)(ws + 15728640);       // 1024x1024 bf16   2,097,152
  __bf16* qh    = (__bf16*)(ws + 17825792);       // [32][2048][64]   8,388,608
  __bf16* kh    = (__bf16*)(ws + 26214400);       // [32][2048][64]   8,388,608
  __bf16* vt    = (__bf16*)(ws + 34603008);       // [32][64][2048]   8,388,608
  __bf16* oh    = (__bf16*)(ws + 42991616);       // 4096x1024 bf16   8,388,608

  prep_all<<<8608, 256, 0, stream>>>(x, Wi, Bi, Ai, Wo, xb, wtot, binb, aeffT, wob);

  // wtot += (B_in @ Aeff)/128  (LoRA folded into weights; in-place on wtot)
  gemm_mfma<128, 128, 128, 128, 3><<<dim3(24, 8), 256, 0, stream>>>(
      binb, aeffT, nullptr, wtot, nullptr, nullptr);
  // qkv = xb @ wtot^T; Q,K -> head layout (K pre-scaled), V -> V^T directly
  gemm_mfma<64, 1024, 1024, 1024, 1><<<dim3(64, 24), 256, 0, stream>>>(
      xb, wtot, nullptr, qh, kh, vt);
  attn_kernel<<<dim3(64, 32), 128, 0, stream>>>(qh, kh, vt, oh);
  // final = O @ Wo^T (fp32 out)
  gemm_mfma<64, 1024, 1024, 1024, 0><<<dim3(64, 8), 256, 0, stream>>>(
      oh, wob, out, nullptr, nullptr, nullptr);
}

// Round 7
// 263.692 us; speedup vs baseline: 1.2674x; 1.2674x over previous
//
#include <hip/hip_runtime.h>

// Problem constants
#define E_DIM 1024
#define H_NUM 16
#define D_HEAD 64
#define SEQ 2048
#define BATCH 2
#define NTOK 4096      // BATCH*SEQ
#define R_LORA 128
#define Q3 3072        // 3*E_DIM
#define K_PRESCALE 0.125f  // 1/sqrt(64), exact in bf16

typedef float floatx4 __attribute__((ext_vector_type(4)));
typedef __bf16 bf16x8 __attribute__((ext_vector_type(8)));
typedef __bf16 bf16x4 __attribute__((ext_vector_type(4)));
typedef bf16x8 bf16x8_al __attribute__((may_alias));
typedef bf16x4 bf16x4_al __attribute__((may_alias));

// async global->LDS, 16B per lane; lds dst must be wave-uniform (HW adds lane*16)
__device__ __forceinline__ void async_cp16(const void* g, void* l) {
  __builtin_amdgcn_global_load_lds(
      (__attribute__((address_space(1))) unsigned int*)(size_t)g,
      (__attribute__((address_space(3))) unsigned int*)l, 16, 0, 0);
}

// ---------------- fused prep kernel (one launch) ----------------
// [0,4096) x->xb | [4096,7168) weff rows (into wtot) | [7168,7552) binb
// [7552,7584) aeffT (fold+transpose) | [7584,8608) wo
__global__ __launch_bounds__(256) void prep_all(const float* __restrict__ x,
                                                const float* __restrict__ Wi,
                                                const float* __restrict__ Bl,
                                                const float* __restrict__ Ai,
                                                const float* __restrict__ Wo,
                                                __bf16* __restrict__ xb,
                                                __bf16* __restrict__ wtot,
                                                __bf16* __restrict__ binb,
                                                __bf16* __restrict__ aeffT,
                                                __bf16* __restrict__ wob) {
  __shared__ __bf16 tile[64][65];
  const int blk = blockIdx.x, t = threadIdx.x;
  if (blk < 4096) {                       // x (4096x1024 fp32) -> xb bf16 (contig)
    int idx = (blk * 256 + t) * 4;
    float4 v = *(const float4*)(x + idx);
    bf16x4 o = {(__bf16)v.x, (__bf16)v.y, (__bf16)v.z, (__bf16)v.w};
    *(bf16x4_al*)(xb + idx) = o;
  } else if (blk < 7168) {                // weff row j: fold 3 E-blocks of W_in -> wtot
    int j = blk - 4096, e = t * 4;
    const float* r = Wi + (size_t)j * Q3;
    float4 a = *(const float4*)(r + e);
    float4 b = *(const float4*)(r + e + 1024);
    float4 c = *(const float4*)(r + e + 2048);
    bf16x4 o = {(__bf16)(a.x + b.x + c.x), (__bf16)(a.y + b.y + c.y),
                (__bf16)(a.z + b.z + c.z), (__bf16)(a.w + b.w + c.w)};
    *(bf16x4_al*)(wtot + (size_t)j * E_DIM + e) = o;
  } else if (blk < 7552) {                // binb: B_in cast, dense [3072][128]
    int idx = (blk - 7168) * 256 + t;     // quad id over 3072x32
    int j = idx >> 5, cq = (idx & 31) * 4;
    float4 v = *(const float4*)(Bl + (size_t)j * R_LORA + cq);
    bf16x4 o = {(__bf16)v.x, (__bf16)v.y, (__bf16)v.z, (__bf16)v.w};
    *(bf16x4_al*)(binb + (size_t)j * R_LORA + cq) = o;
  } else if (blk < 7584) {                // aeffT[e][r] = fold of A_in, via LDS transpose
    int b2 = blk - 7552;
    int r0 = (b2 & 1) * 64, e0 = (b2 >> 1) * 64;
    int c = t & 63, r4 = t >> 6;
#pragma unroll
    for (int i = 0; i < 16; i++) {
      int row = r4 + i * 4;  // local r
      const float* rp = Ai + (size_t)(r0 + row) * Q3 + e0 + c;
      tile[row][c] = (__bf16)(rp[0] + rp[1024] + rp[2048]);
    }
    __syncthreads();
#pragma unroll
    for (int i = 0; i < 16; i++) {
      int er = r4 + i * 4;  // local e
      aeffT[(size_t)(e0 + er) * R_LORA + r0 + c] = tile[c][er];
    }
  } else {                                // wo cast
    int idx = ((blk - 7584) * 256 + t) * 4;
    float4 v = *(const float4*)(Wo + idx);
    bf16x4 o = {(__bf16)v.x, (__bf16)v.y, (__bf16)v.z, (__bf16)v.w};
    *(bf16x4_al*)(wob + idx) = o;
  }
}

// ---------------- 128x128 MFMA GEMM: D[m][n] = sum_k A[m][k]*B[n][k] ----------------
// EPI 0: fp32 store, ldc=1024 (out-proj)
// EPI 1: qkv scatter; Q,K -> [bh][s][d] (K pre-scaled by 0.125); V -> V^T [bh][d][s] b64
// EPI 3: wtot in-place: o0[row*1024+col] += acc*(1/128) (LoRA weight fold)
template <int KTOT, int LDA, int LDB, int EPI>
__global__ __launch_bounds__(256) void gemm_mfma(const __bf16* A, const __bf16* Bm,
                                                 float* fOut, __bf16* o0, __bf16* o1,
                                                 __bf16* o2) {
  __shared__ __bf16 lds[8192];  // A-tile 8x(16x32) frag-blocks, then B-tile
  const int t = threadIdx.x;
  const int wave = t >> 6, lane = t & 63;
  const int wm = wave & 1, wn = wave >> 1;
  const int lr = lane & 15, lq = lane >> 4;
  const int m0 = blockIdx.x * 128, n0 = blockIdx.y * 128;

  floatx4 acc[4][4] = {};
  const __bf16* gA = A + (size_t)(m0 + lr) * LDA + lq * 8;
  const __bf16* gB = Bm + (size_t)(n0 + lr) * LDB + lq * 8;

  for (int kk = 0; kk < KTOT; kk += 32) {
    __syncthreads();  // prior frag reads done before overwrite
    async_cp16(gA + (size_t)(wave * 16) * LDA + kk, lds + wave * 512);
    async_cp16(gA + (size_t)((wave + 4) * 16) * LDA + kk, lds + (wave + 4) * 512);
    async_cp16(gB + (size_t)(wave * 16) * LDB + kk, lds + 4096 + wave * 512);
    async_cp16(gB + (size_t)((wave + 4) * 16) * LDB + kk, lds + 4096 + (wave + 4) * 512);
    __syncthreads();  // drains vmcnt -> staging visible
    bf16x8 af[4], bfr[4];
#pragma unroll
    for (int i = 0; i < 4; i++)
      af[i] = *(const bf16x8_al*)(lds + (wm * 4 + i) * 512 + lane * 8);
#pragma unroll
    for (int j = 0; j < 4; j++)
      bfr[j] = *(const bf16x8_al*)(lds + 4096 + (wn * 4 + j) * 512 + lane * 8);
#pragma unroll
    for (int i = 0; i < 4; i++)
#pragma unroll
      for (int j = 0; j < 4; j++)
        acc[i][j] = __builtin_amdgcn_mfma_f32_16x16x32_bf16(af[i], bfr[j], acc[i][j], 0, 0, 0);
  }

#pragma unroll
  for (int i = 0; i < 4; i++)
#pragma unroll
    for (int j = 0; j < 4; j++) {
      const int row0 = m0 + wm * 64 + i * 16 + lq * 4;  // C/D: row = quad*4+reg
      const int col = n0 + wn * 64 + j * 16 + lr;       // C/D: col = lane&15
      if (EPI == 0) {
#pragma unroll
        for (int r = 0; r < 4; r++)
          fOut[(size_t)(row0 + r) * 1024 + col] = acc[i][j][r];
      } else if (EPI == 3) {
#pragma unroll
        for (int r = 0; r < 4; r++) {
          size_t off = (size_t)(row0 + r) * 1024 + col;
          o0[off] = (__bf16)((float)o0[off] + acc[i][j][r] * (1.0f / 128.0f));
        }
      } else {
        int part = col >> 10, e = col & 1023, h = e >> 6, d = e & 63;
        int b = row0 >> 11, s = row0 & 2047;
        if (part == 2) {
          // V^T [bh][d][s]: 4 consecutive s in one lane -> packed b64 store
          bf16x4 pv;
#pragma unroll
          for (int r = 0; r < 4; r++) pv[r] = (__bf16)acc[i][j][r];
          *(bf16x4_al*)(o2 + ((size_t)(b * H_NUM + h) * D_HEAD + d) * SEQ + s) = pv;
        } else {
#pragma unroll
          for (int r = 0; r < 4; r++) {
            float v = acc[i][j][r];
            if (part == 1) v *= K_PRESCALE;  // fold softmax 1/sqrt(D) into K
            size_t off = ((size_t)(b * H_NUM + h) * SEQ + (s + r)) * D_HEAD + d;
            (part == 0 ? o0 : o1)[off] = (__bf16)v;
          }
        }
      }
    }
}

// ---------------- flash attention v7: v3 body, 128-key staged tiles ----------------
// 64 q-rows/block (16/wave), 4 waves. Stage 128-key K/V per barrier-pair (8 cp16
// per wave), then run the PROVEN v3 64-key compute body twice (halves h=0,1).
// Barriers per key halved vs v3; staging-per-key and P-buffer unchanged.
// LDS 40KB -> 4 blocks/CU (= grid cap). S^T = K x Q; P^T b64 pack via XOR-swizzled
// wave-private LDS; max-free softmax (K pre-scaled 1/8).
__global__ __launch_bounds__(256, 4) void attn_kernel(const __bf16* __restrict__ Q,
                                                      const __bf16* __restrict__ K,
                                                      const __bf16* __restrict__ Vt,
                                                      __bf16* __restrict__ O) {
  __shared__ __bf16 smem[8192 + 8192 + 4096];  // kls[16][512] | vls[16][512] | pls[4][1024]
  __bf16* kls = smem;
  __bf16* vls = smem + 8192;
  const int t = threadIdx.x, wave = t >> 6, lane = t & 63;
  const int lr = lane & 15, lq = lane >> 4;
  __bf16* plsw = smem + 16384 + wave * 1024;  // per-wave P: [q=16][key=64], swizzled chunks
  const int bh = blockIdx.y, q0 = blockIdx.x * 64;
  const size_t hbase = (size_t)bh * SEQ * D_HEAD;
  const __bf16* Kp = K + hbase;
  const __bf16* vtb = Vt + (size_t)bh * D_HEAD * SEQ;
  const int row7 = lr & 7;

  // Q frags (B-operand: rows q = q0+wave*16+lr)
  bf16x8 qf0, qf1;
  {
    const __bf16* qp = Q + hbase + (size_t)(q0 + wave * 16 + lr) * D_HEAD + lq * 8;
    qf0 = *(const bf16x8_al*)qp;
    qf1 = *(const bf16x8_al*)(qp + 32);
  }

  floatx4 oacc[4] = {};
  float lsum = 0.0f;

  for (int kt = 0; kt < SEQ; kt += 128) {
    __syncthreads();  // prior tile's LDS reads complete before overwrite
    // stage 32 segs (8/wave): 0..15 = K (kb=s>>1 of 8, c=s&1), 16..31 = V (dg=v>>2, kc=v&3)
#pragma unroll
    for (int ii = 0; ii < 8; ii++) {
      int s = wave * 8 + ii;
      const __bf16* src;
      if (s < 16) {
        src = Kp + (size_t)(kt + (s >> 1) * 16 + lr) * D_HEAD + (s & 1) * 32 + lq * 8;
      } else {
        int v = s - 16;
        src = vtb + (size_t)((v >> 2) * 16 + lr) * SEQ + kt + (v & 3) * 32 + lq * 8;
      }
      async_cp16(src, smem + s * 512);
    }
    __syncthreads();  // drains vmcnt -> staging visible

#pragma unroll
    for (int h = 0; h < 2; h++) {
      // S^T (keys x q) + softmax + P^T pack — v3 body, key base h*64
#pragma unroll
      for (int kb = 0; kb < 4; kb++) {
        bf16x8 kf0 = *(const bf16x8_al*)(kls + (h * 8 + kb * 2) * 512 + lane * 8);
        bf16x8 kf1 = *(const bf16x8_al*)(kls + (h * 8 + kb * 2 + 1) * 512 + lane * 8);
        floatx4 s = {};
        s = __builtin_amdgcn_mfma_f32_16x16x32_bf16(kf0, qf0, s, 0, 0, 0);
        s = __builtin_amdgcn_mfma_f32_16x16x32_bf16(kf1, qf1, s, 0, 0, 0);
        bf16x4 pv;
#pragma unroll
        for (int r = 0; r < 4; r++) {
          float p = __expf(s[r]);  // 1/sqrt(D) already folded into K
          lsum += p;
          pv[r] = (__bf16)p;
        }
        // lane holds keys (local) kb*16+lq*4+{0..3} for q=lr -> one b64 store
        int chunk = (kb * 2 + (lq >> 1)) ^ row7;
        *(bf16x4_al*)(plsw + lr * 64 + chunk * 8 + (lq & 1) * 4) = pv;
      }

      // O += P @ V : A-frag P[q=lr][key=kc*32+lq*8+j], B-frag Vt[d][key]
#pragma unroll
      for (int kc = 0; kc < 2; kc++) {
        int chunk = (kc * 4 + lq) ^ row7;
        bf16x8 pf = *(const bf16x8_al*)(plsw + lr * 64 + chunk * 8);
#pragma unroll
        for (int jd = 0; jd < 4; jd++) {
          bf16x8 vf = *(const bf16x8_al*)(vls + (jd * 4 + h * 2 + kc) * 512 + lane * 8);
          oacc[jd] = __builtin_amdgcn_mfma_f32_16x16x32_bf16(pf, vf, oacc[jd], 0, 0, 0);
        }
      }
    }
  }

  // reduce l across the 4 lanes sharing q=lr (lq groups)
  lsum += __shfl_xor(lsum, 16);
  lsum += __shfl_xor(lsum, 32);

  const int b = bh >> 4, h = bh & 15;
#pragma unroll
  for (int r = 0; r < 4; r++) {
    float linv = 1.0f / __shfl(lsum, lq * 4 + r);  // lane q_local holds l(q_local)
    int s = q0 + wave * 16 + lq * 4 + r;
#pragma unroll
    for (int jd = 0; jd < 4; jd++) {
      int d = jd * 16 + lr;
      O[((size_t)b * SEQ + s) * E_DIM + h * D_HEAD + d] = (__bf16)(oacc[jd][r] * linv);
    }
  }
}

// ---------------- launch ----------------
extern "C" void kernel_launch(void* const* d_in, const int* in_sizes, int n_in,
                              void* d_out, int out_size, void* d_ws, size_t ws_size,
                              hipStream_t stream) {
  const float* x  = (const float*)d_in[0];
  const float* Wi = (const float*)d_in[1];
  const float* Ai = (const float*)d_in[2];
  const float* Bi = (const float*)d_in[3];
  const float* Wo = (const float*)d_in[4];
  float* out = (float*)d_out;
  char* ws = (char*)d_ws;

  // workspace layout (bytes), ~49 MB
  __bf16* xb    = (__bf16*)(ws);                  // 4096x1024 bf16   8,388,608
  __bf16* wtot  = (__bf16*)(ws + 8388608);        // 3072x1024 bf16   6,291,456
  __bf16* binb  = (__bf16*)(ws + 14680064);       // 3072x128 bf16      786,432
  __bf16* aeffT = (__bf16*)(ws + 15466496);       // 1024x128 bf16      262,144
  __bf16* wob   = (__bf16*)(ws + 15728640);       // 1024x1024 bf16   2,097,152
  __bf16* qh    = (__bf16*)(ws + 17825792);       // [32][2048][64]   8,388,608
  __bf16* kh    = (__bf16*)(ws + 26214400);       // [32][2048][64]   8,388,608
  __bf16* vt    = (__bf16*)(ws + 34603008);       // [32][64][2048]   8,388,608
  __bf16* oh    = (__bf16*)(ws + 42991616);       // 4096x1024 bf16   8,388,608

  prep_all<<<8608, 256, 0, stream>>>(x, Wi, Bi, Ai, Wo, xb, wtot, binb, aeffT, wob);

  // wtot += (B_in @ Aeff)/128  (LoRA folded into weights; in-place on wtot)
  gemm_mfma<128, 128, 128, 3><<<dim3(24, 8), 256, 0, stream>>>(
      binb, aeffT, nullptr, wtot, nullptr, nullptr);
  // qkv = xb @ wtot^T; Q,K -> head layout (K pre-scaled), V -> V^T directly
  gemm_mfma<1024, 1024, 1024, 1><<<dim3(32, 24), 256, 0, stream>>>(
      xb, wtot, nullptr, qh, kh, vt);
  attn_kernel<<<dim3(32, 32), 256, 0, stream>>>(qh, kh, vt, oh);
  // final = O @ Wo^T (fp32 out)
  gemm_mfma<1024, 1024, 1024, 0><<<dim3(32, 8), 256, 0, stream>>>(
      oh, wob, out, nullptr, nullptr, nullptr);
}